// Round 4
// baseline (412.734 us; speedup 1.0000x reference)
//
#include <hip/hip_runtime.h>
#include <math.h>

typedef _Float16 f16;
typedef _Float16 f16x2 __attribute__((ext_vector_type(2)));
typedef _Float16 f16x4 __attribute__((ext_vector_type(4)));
typedef _Float16 f16x8 __attribute__((ext_vector_type(8)));
typedef float    f32x4 __attribute__((ext_vector_type(4)));

#define PKRTZ(a, b) __builtin_bit_cast(f16x2, __builtin_amdgcn_cvt_pkrtz((a), (b)))

#define NN 8192
#define DD 64
#define KT 32            // keys per tile
#define NQB 64           // queries per block
#define NWAVES 8
#define KPW (NN / NWAVES)     // 1024 keys per wave
#define NTILES (KPW / KT)     // 32

// Xt: [d][key] f16, row pitch 40, XOR swizzle: key k stored at
//   d*40 + ((k>>3) ^ ((d>>3)&3))*8 + (k&7)   (max index 2551)
#define XT_BYTES 5200
#define P_PITCH 36            // f16; rows are 72 B: b64 accesses stay 8B-aligned
#define P_BYTES (64 * P_PITCH * 2)      // 4608
#define WAVE_BYTES (XT_BYTES + P_BYTES) // 9808
#define MAIN_BYTES (NWAVES * WAVE_BYTES)// 78464
#define LSTAR_OFF MAIN_BYTES
#define SMEM_BYTES (MAIN_BYTES + 64 * 4)// 78720 -> 2 blocks/CU (16 waves)

// epilogue overlay (inside MAIN region, used after barrier):
// Hl: [d][q] f32, pitch 68; Wl: [d][o] f32, pitch 68
#define HL_PITCH 68
#define WL_OFF (64 * HL_PITCH * 4)      // 17408

#define LOG2E 1.44269504088896f

__global__ __launch_bounds__(512, 4)
void gconv_attn(const float* __restrict__ X, const float* __restrict__ W,
                float* __restrict__ out)
{
  __shared__ __align__(16) unsigned char smem[SMEM_BYTES];

  const int tid  = threadIdx.x;
  const int lane = tid & 63;
  const int wave = tid >> 6;
  const int q15  = lane & 15;
  const int quad = lane >> 4;

  const int batch = blockIdx.x & 3;
  const int qbase = (blockIdx.x >> 2) * NQB;
  const float* Xb = X + (size_t)batch * NN * DD;

  f16* Xt = (f16*)(smem + wave * WAVE_BYTES);
  f16* Pw = (f16*)(smem + wave * WAVE_BYTES + XT_BYTES);

  // ---- Q fragments (B-operand: n=q15 -> query, k=c*32+quad*8+j -> d),
  // scaled by log2e (exp2 domain). Static max m2 = log2e*||x||^2 + slack,
  // computed from the SAME f16 values -> identical in every wave.
  f16x8 qf[4][2];
  float m2[4], lrow[4];
  #pragma unroll
  for (int qt = 0; qt < 4; ++qt) {
    const float* qp = Xb + (size_t)(qbase + qt*16 + q15) * DD + quad*8;
    float nrm = 0.f;
    #pragma unroll
    for (int c = 0; c < 2; ++c) {
      const float4 a = *(const float4*)(qp + c*32);
      const float4 b = *(const float4*)(qp + c*32 + 4);
      float xs[8] = {a.x, a.y, a.z, a.w, b.x, b.y, b.z, b.w};
      f16x8 v;
      #pragma unroll
      for (int e = 0; e < 8; ++e) {
        const f16 ks = (f16)xs[e];            // RTN, same as K-side conversion
        const f16 qs = (f16)(xs[e] * LOG2E);
        nrm += (float)qs * (float)ks;
        v[e] = qs;
      }
      qf[qt][c] = v;
    }
    nrm += __shfl_xor(nrm, 16);
    nrm += __shfl_xor(nrm, 32);
    m2[qt] = nrm + 2.0f;     // p_qq = 2^-2; worst-case off-diag excess ~3 nats -> p <= ~5 (f16-safe)
    lrow[qt] = 0.f;
  }

  f32x4 acc[4][4];  // h^T accumulator, C-layout: row d = mt*16+quad*4+rr, col q = qt*16+q15
  #pragma unroll
  for (int a = 0; a < 4; ++a)
    #pragma unroll
    for (int b = 0; b < 4; ++b)
      acc[a][b] = (f32x4){0.f, 0.f, 0.f, 0.f};

  for (int t = 0; t < NTILES; ++t) {
    const int kbase = wave * KPW + t * KT;

    // ---- K rows straight from global (L2-hot), RTN f16 conversion ----
    // A[m=key=g*16+q15][k=d=c*32+quad*8+j]
    f16x8 ka[2][2];
    #pragma unroll
    for (int g = 0; g < 2; ++g) {
      const float* kp = Xb + (size_t)(kbase + g*16 + q15) * DD + quad*8;
      #pragma unroll
      for (int c = 0; c < 2; ++c) {
        const float4 a = *(const float4*)(kp + c*32);
        const float4 b = *(const float4*)(kp + c*32 + 4);
        f16x8 v;
        v[0]=(f16)a.x; v[1]=(f16)a.y; v[2]=(f16)a.z; v[3]=(f16)a.w;
        v[4]=(f16)b.x; v[5]=(f16)b.y; v[6]=(f16)b.z; v[7]=(f16)b.w;
        ka[g][c] = v;
      }
    }

    // ---- build transposed tile Xt[d][key] from ka regs (XOR swizzle, no wrap bug) ----
    #pragma unroll
    for (int g = 0; g < 2; ++g)
      #pragma unroll
      for (int c = 0; c < 2; ++c) {
        const int bi = ((g*16 + q15) >> 3) ^ quad;  // (key>>3) ^ ((d>>3)&3), since (d>>3)&3==quad here
        #pragma unroll
        for (int j = 0; j < 8; ++j) {
          const int d = c*32 + quad*8 + j;
          Xt[d*40 + bi*8 + (q15 & 7)] = ka[g][c][j];
        }
      }

    // ---- S^T = K.Q^T, static-max exp2, P write ----
    #pragma unroll
    for (int qt = 0; qt < 4; ++qt) {
      #pragma unroll
      for (int g = 0; g < 2; ++g) {
        f32x4 s = (f32x4){0.f, 0.f, 0.f, 0.f};
        s = __builtin_amdgcn_mfma_f32_16x16x32_f16(ka[g][0], qf[qt][0], s, 0, 0, 0);
        s = __builtin_amdgcn_mfma_f32_16x16x32_f16(ka[g][1], qf[qt][1], s, 0, 0, 0);
        // s[rr] = log2e * S[key=g*16+quad*4+rr][query=qt*16+q15]
        const float p0 = __builtin_amdgcn_exp2f(s[0] - m2[qt]);
        const float p1 = __builtin_amdgcn_exp2f(s[1] - m2[qt]);
        const float p2 = __builtin_amdgcn_exp2f(s[2] - m2[qt]);
        const float p3 = __builtin_amdgcn_exp2f(s[3] - m2[qt]);
        lrow[qt] += (p0 + p1) + (p2 + p3);   // deferred l: no in-loop reduction
        union { f16x4 v; f16x2 h[2]; } pu;
        pu.h[0] = PKRTZ(p0, p1);
        pu.h[1] = PKRTZ(p2, p3);
        *(f16x4*)&Pw[(qt*16 + q15)*P_PITCH + g*16 + quad*4] = pu.v;
      }
    }

    // ---- h^T += V^T.P^T ----
    f16x8 va[4];   // A[m=d=mt*16+q15][k=key=quad*8+j]
    #pragma unroll
    for (int mt = 0; mt < 4; ++mt) {
      const int d  = mt*16 + q15;
      const int bi = quad ^ ((d >> 3) & 3);
      va[mt] = *(const f16x8*)&Xt[d*40 + bi*8];
    }
    #pragma unroll
    for (int qt = 0; qt < 4; ++qt) {
      union { f16x8 v; f16x4 h[2]; } pu;
      pu.h[0] = *(const f16x4*)&Pw[(qt*16 + q15)*P_PITCH + quad*8];
      pu.h[1] = *(const f16x4*)&Pw[(qt*16 + q15)*P_PITCH + quad*8 + 4];
      #pragma unroll
      for (int mt = 0; mt < 4; ++mt)
        acc[qt][mt] = __builtin_amdgcn_mfma_f32_16x16x32_f16(va[mt], pu.v, acc[qt][mt], 0, 0, 0);
    }
  }

  // ================= merge across 8 key-split waves (same m2 everywhere: plain sums) =================
  __syncthreads();
  float* Hl    = (float*)smem;                  // [d][q] pitch 68
  float* Wl    = (float*)(smem + WL_OFF);       // [d][o] pitch 68
  float* Lstar = (float*)(smem + LSTAR_OFF);

  for (int i = tid; i < 64*HL_PITCH; i += 512) Hl[i] = 0.f;
  for (int i = tid; i < 64*64; i += 512) Wl[(i >> 6)*HL_PITCH + (i & 63)] = W[i];
  if (tid < 64) Lstar[tid] = 0.f;
  __syncthreads();

  #pragma unroll
  for (int qt = 0; qt < 4; ++qt) {
    float lr = lrow[qt];
    lr += __shfl_xor(lr, 16);
    lr += __shfl_xor(lr, 32);
    if (quad == 0) atomicAdd(&Lstar[qt*16 + q15], lr);
    #pragma unroll
    for (int mt = 0; mt < 4; ++mt)
      #pragma unroll
      for (int rr = 0; rr < 4; ++rr)
        atomicAdd(&Hl[(mt*16 + quad*4 + rr)*HL_PITCH + qt*16 + q15], acc[qt][mt][rr]);
  }
  __syncthreads();

  // ================= projection: out = (H / l) . W =================
  {
    const int qq = tid >> 3;          // 64 queries, 8 threads each
    const int og = (tid & 7) * 8;     // 8 outputs per thread
    f32x4 o0 = (f32x4){0.f,0.f,0.f,0.f}, o1 = (f32x4){0.f,0.f,0.f,0.f};
    for (int d = 0; d < 64; ++d) {
      const float h = Hl[d*HL_PITCH + qq];
      const f32x4 w0 = *(const f32x4*)&Wl[d*HL_PITCH + og];
      const f32x4 w1 = *(const f32x4*)&Wl[d*HL_PITCH + og + 4];
      o0 += h * w0;
      o1 += h * w1;
    }
    const float inv = 1.0f / Lstar[qq];
    float* op = out + ((size_t)batch * NN + qbase + qq) * DD + og;
    *(f32x4*)(op)     = o0 * inv;
    *(f32x4*)(op + 4) = o1 * inv;
  }
}

extern "C" void kernel_launch(void* const* d_in, const int* in_sizes, int n_in,
                              void* d_out, int out_size, void* d_ws, size_t ws_size,
                              hipStream_t stream) {
  const float* X = (const float*)d_in[0];   // [4, 8192, 64] fp32
  const float* W = (const float*)d_in[1];   // [64, 64] fp32
  float* out = (float*)d_out;               // [4, 8192, 64] fp32
  dim3 grid(512), block(512);               // 512 q-tiles of 64 queries, 8 key-split waves
  gconv_attn<<<grid, block, 0, stream>>>(X, W, out);
}

// Round 5
// 225.323 us; speedup vs baseline: 1.8317x; 1.8317x over previous
//
#include <hip/hip_runtime.h>
#include <math.h>

typedef _Float16 f16;
typedef _Float16 f16x2 __attribute__((ext_vector_type(2)));
typedef _Float16 f16x4 __attribute__((ext_vector_type(4)));
typedef _Float16 f16x8 __attribute__((ext_vector_type(8)));
typedef float    f32x4 __attribute__((ext_vector_type(4)));

#define PKRTZ(a, b) __builtin_bit_cast(f16x2, __builtin_amdgcn_cvt_pkrtz((a), (b)))

#define NN 8192
#define DD 64
#define KT 32                  // keys per tile
#define NQB 64                 // queries per block
#define NWAVES 4
#define KPW (NN / NWAVES)      // 2048 keys per wave
#define NTILES (KPW / KT)      // 64

// Xt: [d][key] f16, pitch 40, XOR swizzle: (d,k) at d*40 + ((k>>3)^((d>>3)&3))*8 + (k&7)
#define XT_BYTES 5200
#define P_PITCH 36             // f16 pitch: rows 72 B, b64 ops stay 8B-aligned, <=2-way banks
#define P_BYTES (64 * P_PITCH * 2)       // 4608
#define WAVE_BYTES (XT_BYTES + P_BYTES)  // 9808
#define MAIN_BYTES (NWAVES * WAVE_BYTES) // 39232
#define LSTAR_OFF MAIN_BYTES
#define SMEM_BYTES (MAIN_BYTES + 64 * 4) // 39488

// epilogue overlay inside MAIN region (after barrier):
#define HL_PITCH 68
#define WL_OFF (64 * HL_PITCH * 4)       // 17408; Hl [0,17408), Wl [17408,34816)

#define LOG2E 1.44269504088896f

// 256 threads, bounds (256,2): 256-VGPR cap -> no spill (R4's failure mode was
// (512,4)'s 128-reg cap forcing ~500 MB of scratch traffic). Grid 512 = 2
// blocks/CU; regs up to 256 are free, spent on s/w pipelining the K loads.
__global__ __launch_bounds__(256, 2)
void gconv_attn(const float* __restrict__ X, const float* __restrict__ W,
                float* __restrict__ out)
{
  __shared__ __align__(16) unsigned char smem[SMEM_BYTES];

  const int tid  = threadIdx.x;
  const int lane = tid & 63;
  const int wave = tid >> 6;
  const int q15  = lane & 15;
  const int quad = lane >> 4;

  const int batch = blockIdx.x >> 7;           // proven mapping (R1: 35 MB fetch)
  const int qbase = (blockIdx.x & 127) * NQB;
  const float* Xb = X + (size_t)batch * NN * DD;

  f16* Xt = (f16*)(smem + wave * WAVE_BYTES);
  f16* Pw = (f16*)(smem + wave * WAVE_BYTES + XT_BYTES);

  // ---- Q fragments (B-operand: n=q15 -> query, k=c*32+quad*8+j -> d), exp2 domain.
  // Static max m2 = log2e*||x||^2 + 2 from the same f16 values (identical across waves).
  f16x8 qf[4][2];
  float m2[4], lrow[4];
  #pragma unroll
  for (int qt = 0; qt < 4; ++qt) {
    const float* qp = Xb + (size_t)(qbase + qt*16 + q15) * DD + quad*8;
    float nrm = 0.f;
    #pragma unroll
    for (int c = 0; c < 2; ++c) {
      const float4 a = *(const float4*)(qp + c*32);
      const float4 b = *(const float4*)(qp + c*32 + 4);
      float xs[8] = {a.x, a.y, a.z, a.w, b.x, b.y, b.z, b.w};
      f16x8 v;
      #pragma unroll
      for (int e = 0; e < 8; ++e) {
        const f16 ks = (f16)xs[e];
        const f16 qs = (f16)(xs[e] * LOG2E);
        nrm += (float)qs * (float)ks;
        v[e] = qs;
      }
      qf[qt][c] = v;
    }
    nrm += __shfl_xor(nrm, 16);
    nrm += __shfl_xor(nrm, 32);
    m2[qt] = nrm + 2.0f;
    lrow[qt] = 0.f;
  }

  f32x4 acc[4][4];  // h^T, C-layout: row d = mt*16+quad*4+rr, col q = qt*16+q15
  #pragma unroll
  for (int a = 0; a < 4; ++a)
    #pragma unroll
    for (int b = 0; b < 4; ++b)
      acc[a][b] = (f32x4){0.f, 0.f, 0.f, 0.f};

  // ---- software pipeline: raw f32 loads for tile t+1 in flight over tile t ----
  float4 raw[2][2][2];   // [g][c][half]
  {
    const int kbase = wave * KPW;
    #pragma unroll
    for (int g = 0; g < 2; ++g) {
      const float* kp = Xb + (size_t)(kbase + g*16 + q15) * DD + quad*8;
      #pragma unroll
      for (int c = 0; c < 2; ++c) {
        raw[g][c][0] = *(const float4*)(kp + c*32);
        raw[g][c][1] = *(const float4*)(kp + c*32 + 4);
      }
    }
  }

  for (int t = 0; t < NTILES; ++t) {
    // convert current raw -> f16 A-frags  A[m=key=g*16+q15][k=d=c*32+quad*8+j]
    f16x8 ka[2][2];
    #pragma unroll
    for (int g = 0; g < 2; ++g)
      #pragma unroll
      for (int c = 0; c < 2; ++c) {
        const float4 a = raw[g][c][0];
        const float4 b = raw[g][c][1];
        f16x8 v;
        v[0]=(f16)a.x; v[1]=(f16)a.y; v[2]=(f16)a.z; v[3]=(f16)a.w;
        v[4]=(f16)b.x; v[5]=(f16)b.y; v[6]=(f16)b.z; v[7]=(f16)b.w;
        ka[g][c] = v;
      }

    // issue next tile's loads (uniform; last iter reloads same tile harmlessly)
    {
      const int tn = (t + 1 < NTILES) ? t + 1 : t;
      const int kb = wave * KPW + tn * KT;
      #pragma unroll
      for (int g = 0; g < 2; ++g) {
        const float* kp = Xb + (size_t)(kb + g*16 + q15) * DD + quad*8;
        #pragma unroll
        for (int c = 0; c < 2; ++c) {
          raw[g][c][0] = *(const float4*)(kp + c*32);
          raw[g][c][1] = *(const float4*)(kp + c*32 + 4);
        }
      }
    }

    // ---- transposed tile Xt[d][key] (XOR swizzle) ----
    #pragma unroll
    for (int g = 0; g < 2; ++g)
      #pragma unroll
      for (int c = 0; c < 2; ++c) {
        const int bi = ((g*16 + q15) >> 3) ^ quad;   // (key>>3) ^ ((d>>3)&3)
        #pragma unroll
        for (int j = 0; j < 8; ++j) {
          const int d = c*32 + quad*8 + j;
          Xt[d*40 + bi*8 + (q15 & 7)] = ka[g][c][j];
        }
      }

    // ---- S^T = K.Q^T, static-max exp2, P writes ----
    #pragma unroll
    for (int qt = 0; qt < 4; ++qt) {
      #pragma unroll
      for (int g = 0; g < 2; ++g) {
        f32x4 s = (f32x4){0.f, 0.f, 0.f, 0.f};
        s = __builtin_amdgcn_mfma_f32_16x16x32_f16(ka[g][0], qf[qt][0], s, 0, 0, 0);
        s = __builtin_amdgcn_mfma_f32_16x16x32_f16(ka[g][1], qf[qt][1], s, 0, 0, 0);
        const float p0 = __builtin_amdgcn_exp2f(s[0] - m2[qt]);
        const float p1 = __builtin_amdgcn_exp2f(s[1] - m2[qt]);
        const float p2 = __builtin_amdgcn_exp2f(s[2] - m2[qt]);
        const float p3 = __builtin_amdgcn_exp2f(s[3] - m2[qt]);
        lrow[qt] += (p0 + p1) + (p2 + p3);
        union { f16x4 v; f16x2 h[2]; } pu;
        pu.h[0] = PKRTZ(p0, p1);
        pu.h[1] = PKRTZ(p2, p3);
        *(f16x4*)&Pw[(qt*16 + q15)*P_PITCH + g*16 + quad*4] = pu.v;
      }
    }

    // ---- h^T += V^T.P^T ----
    f16x8 va[4];   // A[m=d=mt*16+q15][k=key=quad*8+j]
    #pragma unroll
    for (int mt = 0; mt < 4; ++mt) {
      const int d  = mt*16 + q15;
      const int bi = quad ^ ((d >> 3) & 3);
      va[mt] = *(const f16x8*)&Xt[d*40 + bi*8];
    }
    #pragma unroll
    for (int qt = 0; qt < 4; ++qt) {
      union { f16x8 v; f16x4 h[2]; } pu;
      pu.h[0] = *(const f16x4*)&Pw[(qt*16 + q15)*P_PITCH + quad*8];
      pu.h[1] = *(const f16x4*)&Pw[(qt*16 + q15)*P_PITCH + quad*8 + 4];
      #pragma unroll
      for (int mt = 0; mt < 4; ++mt)
        acc[qt][mt] = __builtin_amdgcn_mfma_f32_16x16x32_f16(va[mt], pu.v, acc[qt][mt], 0, 0, 0);
    }
  }

  // ========= merge across 4 key-split waves (shared m2: plain sums) =========
  __syncthreads();
  float* Hl    = (float*)smem;                  // [d][q] pitch 68
  float* Wl    = (float*)(smem + WL_OFF);       // [d][o] pitch 68
  float* Lstar = (float*)(smem + LSTAR_OFF);

  for (int i = tid; i < 64*HL_PITCH; i += 256) Hl[i] = 0.f;
  for (int i = tid; i < 64*64; i += 256) Wl[(i >> 6)*HL_PITCH + (i & 63)] = W[i];
  if (tid < 64) Lstar[tid] = 0.f;
  __syncthreads();

  #pragma unroll
  for (int qt = 0; qt < 4; ++qt) {
    float lr = lrow[qt];
    lr += __shfl_xor(lr, 16);
    lr += __shfl_xor(lr, 32);
    if (quad == 0) atomicAdd(&Lstar[qt*16 + q15], lr);
    #pragma unroll
    for (int mt = 0; mt < 4; ++mt)
      #pragma unroll
      for (int rr = 0; rr < 4; ++rr)
        atomicAdd(&Hl[(mt*16 + quad*4 + rr)*HL_PITCH + qt*16 + q15], acc[qt][mt][rr]);
  }
  __syncthreads();

  // ========= projection: out = (H / l) . W =========
  {
    const int qq = tid >> 2;          // 64 queries, 4 threads each
    const int og = (tid & 3) * 16;    // 16 outputs per thread
    f32x4 o[4];
    #pragma unroll
    for (int i = 0; i < 4; ++i) o[i] = (f32x4){0.f,0.f,0.f,0.f};
    for (int d = 0; d < 64; ++d) {
      const float h = Hl[d*HL_PITCH + qq];
      const f32x4* wr = (const f32x4*)&Wl[d*HL_PITCH + og];
      #pragma unroll
      for (int i = 0; i < 4; ++i) o[i] += h * wr[i];
    }
    const float inv = 1.0f / Lstar[qq];
    float* op = out + ((size_t)batch * NN + qbase + qq) * DD + og;
    #pragma unroll
    for (int i = 0; i < 4; ++i)
      *(f32x4*)(op + i*4) = o[i] * inv;
  }
}

extern "C" void kernel_launch(void* const* d_in, const int* in_sizes, int n_in,
                              void* d_out, int out_size, void* d_ws, size_t ws_size,
                              hipStream_t stream) {
  const float* X = (const float*)d_in[0];   // [4, 8192, 64] fp32
  const float* W = (const float*)d_in[1];   // [64, 64] fp32
  float* out = (float*)d_out;               // [4, 8192, 64] fp32
  dim3 grid(512), block(256);               // 512 q-tiles of 64 queries, 4 key-split waves
  gconv_attn<<<grid, block, 0, stream>>>(X, W, out);
}

// Round 6
// 208.585 us; speedup vs baseline: 1.9787x; 1.0802x over previous
//
#include <hip/hip_runtime.h>
#include <math.h>

typedef _Float16 f16;
typedef _Float16 f16x2 __attribute__((ext_vector_type(2)));
typedef _Float16 f16x4 __attribute__((ext_vector_type(4)));
typedef _Float16 f16x8 __attribute__((ext_vector_type(8)));
typedef float    f32x4 __attribute__((ext_vector_type(4)));

#define PKRTZ(a, b) __builtin_bit_cast(f16x2, __builtin_amdgcn_cvt_pkrtz((a), (b)))

#define NN 8192
#define DD 64
#define KT 32
#define NQB 64
#define NWAVES 4
#define KPW (NN / NWAVES)      // 2048 keys per wave
#define NTILES (KPW / KT)      // 64

#define LOG2E 1.44269504088896f

// ---------------- kernel A: f32 -> f16 natural (Xn) + 32-key-tiled transpose (Xv) ----
// Xn: [b][n][d] f16.  Xv: [b][kt][d][k'] f16, kt = key-tile of 32, k' = key within tile.
__global__ __launch_bounds__(256, 2)
void prep_f16(const float* __restrict__ X, f16* __restrict__ Xn, f16* __restrict__ Xv)
{
  __shared__ f16 Lt[64 * 72];          // 64 keys x 64 d, pitch 72
  const int tid  = threadIdx.x;
  const int b    = blockIdx.x >> 7;
  const int kb64 = (blockIdx.x & 127) * 64;

  // phase 1: coalesced read, cvt, write Xn + stash in LDS
  {
    const int r = tid >> 2;            // key row 0..63
    const int c = (tid & 3) * 16;      // d col group
    const float* p = X + ((size_t)(b * NN + kb64 + r)) * DD + c;
    const float4 a0 = *(const float4*)(p);
    const float4 a1 = *(const float4*)(p + 4);
    const float4 a2 = *(const float4*)(p + 8);
    const float4 a3 = *(const float4*)(p + 12);
    f16x8 v0, v1;
    v0[0]=(f16)a0.x; v0[1]=(f16)a0.y; v0[2]=(f16)a0.z; v0[3]=(f16)a0.w;
    v0[4]=(f16)a1.x; v0[5]=(f16)a1.y; v0[6]=(f16)a1.z; v0[7]=(f16)a1.w;
    v1[0]=(f16)a2.x; v1[1]=(f16)a2.y; v1[2]=(f16)a2.z; v1[3]=(f16)a2.w;
    v1[4]=(f16)a3.x; v1[5]=(f16)a3.y; v1[6]=(f16)a3.z; v1[7]=(f16)a3.w;
    f16* dn = Xn + ((size_t)(b * NN + kb64 + r)) * DD + c;
    *(f16x8*)(dn)     = v0;
    *(f16x8*)(dn + 8) = v1;
    *(f16x8*)&Lt[r * 72 + c]     = v0;
    *(f16x8*)&Lt[r * 72 + c + 8] = v1;
  }
  __syncthreads();
  // phase 2: write transposed tiles (threads 0..127: one d-row of one 32-key half)
  if (tid < 128) {
    const int h = tid >> 6;            // which 32-key half
    const int d = tid & 63;
    union { f16 s[32]; f16x8 v[4]; } u;
    #pragma unroll
    for (int j = 0; j < 32; ++j) u.s[j] = Lt[(h * 32 + j) * 72 + d];
    const int kt = (kb64 >> 5) + h;    // global 32-key tile index
    f16* dst = Xv + (((size_t)(b * (NN / 32) + kt)) * DD + d) * 32;
    #pragma unroll
    for (int i = 0; i < 4; ++i) *(f16x8*)&dst[i * 8] = u.v[i];
  }
}

// ---------------- kernel B: attention + projection ----------------
// LDS: main loop uses only per-wave P scratch; epilogue overlays Hl/Wl/Lstar.
#define P_PITCH 36                       // f16; rows 72 B, b64 ops 8B-aligned, <=2-way banks
#define P_BYTES (64 * P_PITCH * 2)       // 4608 per wave
#define HL_PITCH 68
#define WL_OFF  (64 * HL_PITCH * 4)      // 17408
#define LST_OFF (2 * 64 * HL_PITCH * 4)  // 34816
#define SMEM_B  (LST_OFF + 64 * 4)       // 35072

struct Frag { f16x8 ka[2][2]; f16x8 vb[4]; };

__global__ __launch_bounds__(256, 2)
void gconv_attn(const float* __restrict__ X, const f16* __restrict__ Xn,
                const f16* __restrict__ Xv, const float* __restrict__ W,
                float* __restrict__ out)
{
  __shared__ __align__(16) unsigned char smem[SMEM_B];

  const int tid  = threadIdx.x;
  const int lane = tid & 63;
  const int wave = tid >> 6;
  const int q15  = lane & 15;
  const int quad = lane >> 4;

  const int batch = blockIdx.x >> 7;
  const int qbase = (blockIdx.x & 127) * NQB;
  const float* Xb = X + (size_t)batch * NN * DD;

  f16* Pw = (f16*)(smem + wave * P_BYTES);

  // wave-local bases
  const f16* XnW = Xn + ((size_t)batch * NN + wave * KPW) * DD + q15 * DD + quad * 8;
  const f16* XvW = Xv + (((size_t)batch * (NN / 32) + wave * NTILES)) * DD * 32
                      + q15 * 32 + quad * 8;

  // ---- Q fragments (B-operand: n=q15 query, k=c*32+quad*8+j d), exp2 domain ----
  f16x8 qf[4][2];
  float m2[4], lrow[4];
  #pragma unroll
  for (int qt = 0; qt < 4; ++qt) {
    const float* qp = Xb + (size_t)(qbase + qt*16 + q15) * DD + quad*8;
    float nrm = 0.f;
    #pragma unroll
    for (int c = 0; c < 2; ++c) {
      const float4 a = *(const float4*)(qp + c*32);
      const float4 b = *(const float4*)(qp + c*32 + 4);
      float xs[8] = {a.x, a.y, a.z, a.w, b.x, b.y, b.z, b.w};
      f16x8 v;
      #pragma unroll
      for (int e = 0; e < 8; ++e) {
        const f16 ks = (f16)xs[e];
        const f16 qs = (f16)(xs[e] * LOG2E);
        nrm += (float)qs * (float)ks;
        v[e] = qs;
      }
      qf[qt][c] = v;
    }
    nrm += __shfl_xor(nrm, 16);
    nrm += __shfl_xor(nrm, 32);
    m2[qt] = nrm + 2.0f;
    lrow[qt] = 0.f;
  }

  f32x4 acc[4][4];
  #pragma unroll
  for (int a = 0; a < 4; ++a)
    #pragma unroll
    for (int b = 0; b < 4; ++b)
      acc[a][b] = (f32x4){0.f, 0.f, 0.f, 0.f};

  auto load_frag = [&](Frag& f, int t) {
    const f16* kn = XnW + (size_t)t * (KT * DD);
    #pragma unroll
    for (int g = 0; g < 2; ++g)
      #pragma unroll
      for (int c = 0; c < 2; ++c)
        f.ka[g][c] = *(const f16x8*)(kn + g * 16 * DD + c * 32);
    const f16* vn = XvW + (size_t)t * (DD * 32);
    #pragma unroll
    for (int mt = 0; mt < 4; ++mt)
      f.vb[mt] = *(const f16x8*)(vn + mt * 16 * 32);
  };

  auto process = [&](const Frag& f) {
    #pragma unroll
    for (int qt = 0; qt < 4; ++qt) {
      #pragma unroll
      for (int g = 0; g < 2; ++g) {
        f32x4 s = (f32x4){0.f, 0.f, 0.f, 0.f};
        s = __builtin_amdgcn_mfma_f32_16x16x32_f16(f.ka[g][0], qf[qt][0], s, 0, 0, 0);
        s = __builtin_amdgcn_mfma_f32_16x16x32_f16(f.ka[g][1], qf[qt][1], s, 0, 0, 0);
        const float p0 = __builtin_amdgcn_exp2f(s[0] - m2[qt]);
        const float p1 = __builtin_amdgcn_exp2f(s[1] - m2[qt]);
        const float p2 = __builtin_amdgcn_exp2f(s[2] - m2[qt]);
        const float p3 = __builtin_amdgcn_exp2f(s[3] - m2[qt]);
        lrow[qt] += (p0 + p1) + (p2 + p3);
        union { f16x4 v; f16x2 h[2]; } pu;
        pu.h[0] = PKRTZ(p0, p1);
        pu.h[1] = PKRTZ(p2, p3);
        *(f16x4*)&Pw[(qt*16 + q15)*P_PITCH + g*16 + quad*4] = pu.v;
      }
    }
    #pragma unroll
    for (int qt = 0; qt < 4; ++qt) {
      union { f16x8 v; f16x4 h[2]; } pu;
      pu.h[0] = *(const f16x4*)&Pw[(qt*16 + q15)*P_PITCH + quad*8];
      pu.h[1] = *(const f16x4*)&Pw[(qt*16 + q15)*P_PITCH + quad*8 + 4];
      #pragma unroll
      for (int mt = 0; mt < 4; ++mt)
        acc[qt][mt] = __builtin_amdgcn_mfma_f32_16x16x32_f16(f.vb[mt], pu.v, acc[qt][mt], 0, 0, 0);
    }
  };

  // ---- software-pipelined main loop (register double-buffer) ----
  Frag f0, f1;
  load_frag(f0, 0);
  for (int t = 0; t < NTILES; t += 2) {
    const int t1 = (t + 1 < NTILES) ? t + 1 : t;
    const int t2 = (t + 2 < NTILES) ? t + 2 : t1;
    load_frag(f1, t1);
    process(f0);
    load_frag(f0, t2);
    process(f1);
  }

  // ========= merge across 4 key-split waves (shared m2: plain sums) =========
  __syncthreads();
  float* Hl    = (float*)smem;
  float* Wl    = (float*)(smem + WL_OFF);
  float* Lstar = (float*)(smem + LST_OFF);

  for (int i = tid; i < 64*HL_PITCH; i += 256) Hl[i] = 0.f;
  for (int i = tid; i < 64*64; i += 256) Wl[(i >> 6)*HL_PITCH + (i & 63)] = W[i];
  if (tid < 64) Lstar[tid] = 0.f;
  __syncthreads();

  #pragma unroll
  for (int qt = 0; qt < 4; ++qt) {
    float lr = lrow[qt];
    lr += __shfl_xor(lr, 16);
    lr += __shfl_xor(lr, 32);
    if (quad == 0) atomicAdd(&Lstar[qt*16 + q15], lr);
    #pragma unroll
    for (int mt = 0; mt < 4; ++mt)
      #pragma unroll
      for (int rr = 0; rr < 4; ++rr)
        atomicAdd(&Hl[(mt*16 + quad*4 + rr)*HL_PITCH + qt*16 + q15], acc[qt][mt][rr]);
  }
  __syncthreads();

  // ========= projection: out = (H / l) . W =========
  {
    const int qq = tid >> 2;
    const int og = (tid & 3) * 16;
    f32x4 o[4];
    #pragma unroll
    for (int i = 0; i < 4; ++i) o[i] = (f32x4){0.f,0.f,0.f,0.f};
    for (int d = 0; d < 64; ++d) {
      const float h = Hl[d*HL_PITCH + qq];
      const f32x4* wr = (const f32x4*)&Wl[d*HL_PITCH + og];
      #pragma unroll
      for (int i = 0; i < 4; ++i) o[i] += h * wr[i];
    }
    const float inv = 1.0f / Lstar[qq];
    float* op = out + ((size_t)batch * NN + qbase + qq) * DD + og;
    #pragma unroll
    for (int i = 0; i < 4; ++i)
      *(f32x4*)(op + i*4) = o[i] * inv;
  }
}

extern "C" void kernel_launch(void* const* d_in, const int* in_sizes, int n_in,
                              void* d_out, int out_size, void* d_ws, size_t ws_size,
                              hipStream_t stream) {
  const float* X = (const float*)d_in[0];   // [4, 8192, 64] fp32
  const float* W = (const float*)d_in[1];   // [64, 64] fp32
  float* out = (float*)d_out;               // [4, 8192, 64] fp32

  f16* Xn = (f16*)d_ws;                                  // 4 MiB
  f16* Xv = (f16*)((char*)d_ws + (size_t)4 * NN * DD * 2); // 4 MiB
  prep_f16<<<dim3(512), dim3(256), 0, stream>>>(X, Xn, Xv);
  gconv_attn<<<dim3(512), dim3(256), 0, stream>>>(X, Xn, Xv, W, out);
}